// Round 1
// baseline (732.731 us; speedup 1.0000x reference)
//
#include <hip/hip_runtime.h>
#include <math.h>

#define P_NODES 30000
#define DIN_    1536
#define DOUT_   256
#define E_EDGES 320000
#define ET      (E_EDGES + P_NODES)
#define NEG     0.2f

typedef float  f32x4  __attribute__((ext_vector_type(4)));
typedef __bf16 bf16x8 __attribute__((ext_vector_type(8)));
typedef __bf16 bf16x4 __attribute__((ext_vector_type(4)));

// ---------------- weight prep: transpose + bf16 cast ----------------
__global__ __launch_bounds__(256)
void prep_w1(const float* __restrict__ W1l, const float* __restrict__ W1r,
             const float* __restrict__ resW, __bf16* __restrict__ WT1)
{
    int idx = blockIdx.x * 256 + threadIdx.x;       // DIN_ * 192 threads
    if (idx >= DIN_ * 192) return;
    int k = idx / 192;
    int n0 = (idx - k * 192) * 4;
    const float* src; int col;
    if (n0 < 256)      { src = W1l;  col = n0; }
    else if (n0 < 512) { src = W1r;  col = n0 - 256; }
    else               { src = resW; col = n0 - 512; }
    f32x4 v = *(const f32x4*)(src + (size_t)k * DOUT_ + col);
    #pragma unroll
    for (int j = 0; j < 4; ++j)
        WT1[(size_t)(n0 + j) * DIN_ + k] = (__bf16)v[j];
}

__global__ __launch_bounds__(256)
void prep_w2(const float* __restrict__ W2l, const float* __restrict__ W2r,
             __bf16* __restrict__ WT2)
{
    int idx = blockIdx.x * 256 + threadIdx.x;       // 256 * 128 threads
    if (idx >= 256 * 128) return;
    int k = idx / 128;
    int n0 = (idx - k * 128) * 4;
    const float* src; int col;
    if (n0 < 256) { src = W2l; col = n0; }
    else          { src = W2r; col = n0 - 256; }
    f32x4 v = *(const f32x4*)(src + (size_t)k * DOUT_ + col);
    #pragma unroll
    for (int j = 0; j < 4; ++j)
        WT2[(size_t)(n0 + j) * DOUT_ + k] = (__bf16)v[j];
}

__global__ void prep_bias(const float* b1l, const float* b1r, const float* resb,
                          const float* b2l, const float* b2r,
                          float* B1, float* B2)
{
    int t = threadIdx.x;
    if (t < 256)      B1[t] = b1l[t];
    else if (t < 512) B1[t] = b1r[t - 256];
    else if (t < 768) B1[t] = resb[t - 512];
    if (t < 256)      B2[t] = b2l[t];
    else if (t < 512) B2[t] = b2r[t - 256];
}

// ---------------- CSR build ----------------
__global__ void init_deg(int* deg)
{
    int i = blockIdx.x * 256 + threadIdx.x;
    if (i < P_NODES) deg[i] = 1;                    // self loop
}

__global__ void hist_kernel(const int* __restrict__ dst, int* __restrict__ deg)
{
    int e = blockIdx.x * 256 + threadIdx.x;
    if (e < E_EDGES) atomicAdd(&deg[dst[e]], 1);
}

__global__ __launch_bounds__(1024)
void scan_kernel(const int* __restrict__ deg, int* __restrict__ offs, int* __restrict__ pos)
{
    __shared__ int sb[1024];
    const int t = threadIdx.x;
    const int base = t * 30;
    int ldv[30];
    int lsum = 0;
    #pragma unroll
    for (int i = 0; i < 30; ++i) {
        int idx = base + i;
        int v = (idx < P_NODES) ? deg[idx] : 0;
        ldv[i] = v; lsum += v;
    }
    sb[t] = lsum; __syncthreads();
    for (int off = 1; off < 1024; off <<= 1) {
        int v = (t >= off) ? sb[t - off] : 0;
        __syncthreads();
        sb[t] += v;
        __syncthreads();
    }
    int excl = sb[t] - lsum;
    #pragma unroll
    for (int i = 0; i < 30; ++i) {
        int idx = base + i;
        if (idx < P_NODES) { offs[idx] = excl; pos[idx] = excl; excl += ldv[i]; }
    }
    if (t == 0) offs[P_NODES] = ET;
}

__global__ void scatter_kernel(const int* __restrict__ ei, int* __restrict__ pos,
                               int* __restrict__ srcs)
{
    int tgt = blockIdx.x * 256 + threadIdx.x;
    if (tgt < E_EDGES) {
        int s = ei[tgt];
        int d = ei[E_EDGES + tgt];
        int p = atomicAdd(&pos[d], 1);
        srcs[p] = s;
    } else if (tgt < ET) {
        int i = tgt - E_EDGES;
        int p = atomicAdd(&pos[i], 1);
        srcs[p] = i;                                 // self loop
    }
}

// ---------------- bf16 MFMA GEMM: C[M][N] = A[M][K] @ WT[N][K]^T + bias ----------------
// tile 128x128, BK=32, 4 waves; XOR-swizzled LDS (16B granule g ^= (row>>1)&3)
template<bool A_F32>
__global__ __launch_bounds__(256)
void gemm_kernel(const void* __restrict__ Av, const __bf16* __restrict__ WT,
                 const float* __restrict__ bias, float* __restrict__ C,
                 int M, int N, int K, int ntiles)
{
    __shared__ __align__(16) __bf16 As[128 * 32];
    __shared__ __align__(16) __bf16 Bs[128 * 32];

    const int bid = blockIdx.x;
    const int mt = bid / ntiles, nt = bid - mt * ntiles;
    const int grow = mt * 128, gcol = nt * 128;
    const int t = threadIdx.x;
    const int lane = t & 63, wave = t >> 6;
    const int wr = wave >> 1, wc = wave & 1;
    const int fr = lane & 15, kg = lane >> 4;

    const int srow = t >> 1, shalf = t & 1;
    int arow = grow + srow; if (arow > M - 1) arow = M - 1;
    const int swz = (srow >> 1) & 3;
    const int g0 = shalf * 2;

    f32x4 acc[4][4] = {};

    for (int k0 = 0; k0 < K; k0 += 32) {
        bf16x8 a0, a1, b0, b1;
        if constexpr (A_F32) {
            const float* ap = (const float*)Av + (size_t)arow * K + k0 + shalf * 16;
            f32x4 v0 = *(const f32x4*)(ap + 0);
            f32x4 v1 = *(const f32x4*)(ap + 4);
            f32x4 v2 = *(const f32x4*)(ap + 8);
            f32x4 v3 = *(const f32x4*)(ap + 12);
            #pragma unroll
            for (int j = 0; j < 4; ++j) {
                a0[j] = (__bf16)v0[j]; a0[j + 4] = (__bf16)v1[j];
                a1[j] = (__bf16)v2[j]; a1[j + 4] = (__bf16)v3[j];
            }
        } else {
            const __bf16* ap = (const __bf16*)Av + (size_t)arow * K + k0 + shalf * 16;
            a0 = *(const bf16x8*)(ap);
            a1 = *(const bf16x8*)(ap + 8);
        }
        {
            const __bf16* bp = WT + (size_t)(gcol + srow) * K + k0 + shalf * 16;
            b0 = *(const bf16x8*)(bp);
            b1 = *(const bf16x8*)(bp + 8);
        }
        __syncthreads();   // protect previous iteration's LDS reads
        *(bf16x8*)&As[srow * 32 + ((g0    ) ^ swz) * 8] = a0;
        *(bf16x8*)&As[srow * 32 + ((g0 + 1) ^ swz) * 8] = a1;
        *(bf16x8*)&Bs[srow * 32 + ((g0    ) ^ swz) * 8] = b0;
        *(bf16x8*)&Bs[srow * 32 + ((g0 + 1) ^ swz) * 8] = b1;
        __syncthreads();

        bf16x8 af[4], bf[4];
        #pragma unroll
        for (int mi = 0; mi < 4; ++mi) {
            int r = wr * 64 + mi * 16 + fr;
            af[mi] = *(const bf16x8*)&As[r * 32 + (kg ^ ((r >> 1) & 3)) * 8];
        }
        #pragma unroll
        for (int ni = 0; ni < 4; ++ni) {
            int r = wc * 64 + ni * 16 + fr;
            bf[ni] = *(const bf16x8*)&Bs[r * 32 + (kg ^ ((r >> 1) & 3)) * 8];
        }
        #pragma unroll
        for (int mi = 0; mi < 4; ++mi)
            #pragma unroll
            for (int ni = 0; ni < 4; ++ni)
                acc[mi][ni] = __builtin_amdgcn_mfma_f32_16x16x32_bf16(af[mi], bf[ni], acc[mi][ni], 0, 0, 0);
    }

    #pragma unroll
    for (int mi = 0; mi < 4; ++mi) {
        #pragma unroll
        for (int ni = 0; ni < 4; ++ni) {
            int col = gcol + wc * 64 + ni * 16 + fr;
            float bv = bias[col];
            #pragma unroll
            for (int j = 0; j < 4; ++j) {
                int row = grow + wr * 64 + mi * 16 + kg * 4 + j;
                if (row < M) C[(size_t)row * N + col] = acc[mi][ni][j] + bv;
            }
        }
    }
}

// ---------------- GATv2 edge aggregation: one wave per destination node ----------------
// XLXR: [P][ld] with xl at col 0..255, xr at col 256..511
__global__ __launch_bounds__(256)
void gat_kernel(const float* __restrict__ XLXR, int ld,
                const int* __restrict__ offs, const int* __restrict__ srcs,
                const float* __restrict__ att, const float* __restrict__ bias,
                float* __restrict__ out)
{
    const int node = blockIdx.x * 4 + (threadIdx.x >> 6);
    const int lane = threadIdx.x & 63;
    const int c0 = lane * 4;                        // lanes 0-31: head0, 32-63: head1
    f32x4 xr = *(const f32x4*)(XLXR + (size_t)node * ld + 256 + c0);
    f32x4 at = *(const f32x4*)(att + c0);
    f32x4 acc = {0.f, 0.f, 0.f, 0.f};
    float m = -INFINITY, den = 0.f;
    const int e1 = offs[node + 1];
    for (int e = offs[node]; e < e1; ++e) {
        int s = srcs[e];
        f32x4 xl = *(const f32x4*)(XLXR + (size_t)s * ld + c0);
        float p = 0.f;
        #pragma unroll
        for (int j = 0; j < 4; ++j) {
            float tt = xl[j] + xr[j];
            float lr = tt > 0.f ? tt : NEG * tt;
            p = fmaf(at[j], lr, p);
        }
        #pragma unroll
        for (int w = 1; w < 32; w <<= 1) p += __shfl_xor(p, w, 32);
        float nm = fmaxf(m, p);
        float sc = __expf(m - nm);                  // m = -inf -> 0
        float wv = __expf(p - nm);
        den = den * sc + wv;
        #pragma unroll
        for (int j = 0; j < 4; ++j) acc[j] = acc[j] * sc + wv * xl[j];
        m = nm;
    }
    float inv = 1.f / den;
    f32x4 o;
    #pragma unroll
    for (int j = 0; j < 4; ++j) o[j] = acc[j] * inv + bias[c0 + j];
    *(f32x4*)(out + (size_t)node * DOUT_ + c0) = o;
}

// ---------------- h1 = elu(LN(gat1)) + res ; also bf16 copy ----------------
__global__ __launch_bounds__(256)
void h1_kernel(const float* __restrict__ GAT, const float* __restrict__ RESbase, int resld,
               const float* __restrict__ g, const float* __restrict__ b,
               float* __restrict__ H1, __bf16* __restrict__ H1B)
{
    const int node = blockIdx.x * 4 + (threadIdx.x >> 6);
    const int lane = threadIdx.x & 63;
    const int c0 = lane * 4;
    f32x4 h = *(const f32x4*)(GAT + (size_t)node * DOUT_ + c0);
    float s = h[0] + h[1] + h[2] + h[3];
    #pragma unroll
    for (int w = 1; w < 64; w <<= 1) s += __shfl_xor(s, w, 64);
    float mu = s * (1.f / DOUT_);
    f32x4 d; float sq = 0.f;
    #pragma unroll
    for (int j = 0; j < 4; ++j) { d[j] = h[j] - mu; sq += d[j] * d[j]; }
    #pragma unroll
    for (int w = 1; w < 64; w <<= 1) sq += __shfl_xor(sq, w, 64);
    float rs = rsqrtf(sq * (1.f / DOUT_) + 1e-5f);
    f32x4 res = *(const f32x4*)(RESbase + (size_t)node * resld + c0);
    f32x4 o; bf16x4 hb;
    #pragma unroll
    for (int j = 0; j < 4; ++j) {
        float y = d[j] * rs * g[c0 + j] + b[c0 + j];
        float e = y > 0.f ? y : __expf(y) - 1.f;
        o[j] = e + res[j];
        hb[j] = (__bf16)o[j];
    }
    *(f32x4*)(H1 + (size_t)node * DOUT_ + c0) = o;
    *(bf16x4*)(H1B + (size_t)node * DOUT_ + c0) = hb;
}

// ---------------- out = max(h1, elu(LN(gat2)) + h1) ----------------
__global__ __launch_bounds__(256)
void final_kernel(const float* __restrict__ GAT2, const float* __restrict__ H1,
                  const float* __restrict__ g, const float* __restrict__ b,
                  float* __restrict__ out)
{
    const int node = blockIdx.x * 4 + (threadIdx.x >> 6);
    const int lane = threadIdx.x & 63;
    const int c0 = lane * 4;
    f32x4 h = *(const f32x4*)(GAT2 + (size_t)node * DOUT_ + c0);
    float s = h[0] + h[1] + h[2] + h[3];
    #pragma unroll
    for (int w = 1; w < 64; w <<= 1) s += __shfl_xor(s, w, 64);
    float mu = s * (1.f / DOUT_);
    f32x4 d; float sq = 0.f;
    #pragma unroll
    for (int j = 0; j < 4; ++j) { d[j] = h[j] - mu; sq += d[j] * d[j]; }
    #pragma unroll
    for (int w = 1; w < 64; w <<= 1) sq += __shfl_xor(sq, w, 64);
    float rs = rsqrtf(sq * (1.f / DOUT_) + 1e-5f);
    f32x4 h1v = *(const f32x4*)(H1 + (size_t)node * DOUT_ + c0);
    f32x4 o;
    #pragma unroll
    for (int j = 0; j < 4; ++j) {
        float y = d[j] * rs * g[c0 + j] + b[c0 + j];
        float e = y > 0.f ? y : __expf(y) - 1.f;
        float h2 = e + h1v[j];
        o[j] = fmaxf(h1v[j], h2);
    }
    *(f32x4*)(out + (size_t)node * DOUT_ + c0) = o;
}

// ---------------- launch ----------------
extern "C" void kernel_launch(void* const* d_in, const int* in_sizes, int n_in,
                              void* d_out, int out_size, void* d_ws, size_t ws_size,
                              hipStream_t stream)
{
    const float* x     = (const float*)d_in[0];
    const int*   ei    = (const int*)d_in[1];
    const float* W1l   = (const float*)d_in[2];
    const float* b1l   = (const float*)d_in[3];
    const float* W1r   = (const float*)d_in[4];
    const float* b1r   = (const float*)d_in[5];
    const float* att1  = (const float*)d_in[6];
    const float* bias1 = (const float*)d_in[7];
    const float* W2l   = (const float*)d_in[8];
    const float* b2l   = (const float*)d_in[9];
    const float* W2r   = (const float*)d_in[10];
    const float* b2r   = (const float*)d_in[11];
    const float* att2  = (const float*)d_in[12];
    const float* bias2 = (const float*)d_in[13];
    const float* ln1g  = (const float*)d_in[14];
    const float* ln1b  = (const float*)d_in[15];
    const float* ln2g  = (const float*)d_in[16];
    const float* ln2b  = (const float*)d_in[17];
    const float* resW  = (const float*)d_in[18];
    const float* resb  = (const float*)d_in[19];
    float* out = (float*)d_out;

    char* w = (char*)d_ws;
    auto alloc = [&](size_t bytes) {
        char* r = w;
        w += (bytes + 255) & ~(size_t)255;
        return r;
    };
    float*  C     = (float*)alloc((size_t)P_NODES * 768 * 4);   // XL|XR|RES, later XL2|XR2
    float*  GAT   = (float*)alloc((size_t)P_NODES * 256 * 4);
    float*  H1    = (float*)alloc((size_t)P_NODES * 256 * 4);
    __bf16* H1B   = (__bf16*)alloc((size_t)P_NODES * 256 * 2);
    __bf16* WT1   = (__bf16*)alloc((size_t)768 * DIN_ * 2);
    __bf16* WT2   = (__bf16*)alloc((size_t)512 * DOUT_ * 2);
    float*  BIAS1 = (float*)alloc(768 * 4);
    float*  BIAS2 = (float*)alloc(512 * 4);
    int*    deg   = (int*)alloc((size_t)P_NODES * 4);
    int*    offs  = (int*)alloc((size_t)(P_NODES + 1) * 4);
    int*    pos   = (int*)alloc((size_t)(P_NODES + 1) * 4);
    int*    srcs  = (int*)alloc((size_t)ET * 4);

    // weight prep + CSR build
    prep_w1<<<(DIN_ * 192 + 255) / 256, 256, 0, stream>>>(W1l, W1r, resW, WT1);
    prep_w2<<<(256 * 128 + 255) / 256, 256, 0, stream>>>(W2l, W2r, WT2);
    prep_bias<<<1, 1024, 0, stream>>>(b1l, b1r, resb, b2l, b2r, BIAS1, BIAS2);
    init_deg<<<(P_NODES + 255) / 256, 256, 0, stream>>>(deg);
    hist_kernel<<<(E_EDGES + 255) / 256, 256, 0, stream>>>(ei + E_EDGES, deg);
    scan_kernel<<<1, 1024, 0, stream>>>(deg, offs, pos);
    scatter_kernel<<<(ET + 255) / 256, 256, 0, stream>>>(ei, pos, srcs);

    const int mtiles = (P_NODES + 127) / 128;   // 235

    // layer 1
    gemm_kernel<true><<<mtiles * 6, 256, 0, stream>>>(x, WT1, BIAS1, C, P_NODES, 768, DIN_, 6);
    gat_kernel<<<P_NODES / 4, 256, 0, stream>>>(C, 768, offs, srcs, att1, bias1, GAT);
    h1_kernel<<<P_NODES / 4, 256, 0, stream>>>(GAT, C + 512, 768, ln1g, ln1b, H1, H1B);

    // layer 2
    gemm_kernel<false><<<mtiles * 4, 256, 0, stream>>>(H1B, WT2, BIAS2, C, P_NODES, 512, DOUT_, 4);
    gat_kernel<<<P_NODES / 4, 256, 0, stream>>>(C, 512, offs, srcs, att2, bias2, GAT);
    final_kernel<<<P_NODES / 4, 256, 0, stream>>>(GAT, H1, ln2g, ln2b, out);
}

// Round 3
// 659.652 us; speedup vs baseline: 1.1108x; 1.1108x over previous
//
#include <hip/hip_runtime.h>
#include <math.h>

#define P_NODES 30000
#define P_PAD   30080          // 235 * 128
#define DIN_    1536
#define DOUT_   256
#define E_EDGES 320000
#define ET      (E_EDGES + P_NODES)
#define NEG     0.2f

typedef float  f32x4  __attribute__((ext_vector_type(4)));
typedef __bf16 bf16x8 __attribute__((ext_vector_type(8)));
typedef __bf16 bf16x4 __attribute__((ext_vector_type(4)));

// swizzled column for storage feeding global_load_lds-staged GEMM A/B:
// within each 64-col chunk, 16B granule g goes to position g ^ (row & 7)
__device__ __forceinline__ int swz_col(int c, int row) {
    return (c & ~63) | ((((c >> 3) ^ row) & 7) << 3) | (c & 7);
}

// ---------------- x -> bf16, pre-swizzled, rows padded to P_PAD ----------------
__global__ __launch_bounds__(256)
void cast_x(const float* __restrict__ x, __bf16* __restrict__ XB)
{
    int idx = blockIdx.x * 256 + threadIdx.x;      // P_PAD * 192
    if (idx >= P_PAD * 192) return;
    int row = idx / 192;
    int c = (idx - row * 192) * 8;
    int cs = swz_col(c, row);
    bf16x8 o;
    if (row < P_NODES) {
        f32x4 v0 = *(const f32x4*)(x + (size_t)row * DIN_ + c);
        f32x4 v1 = *(const f32x4*)(x + (size_t)row * DIN_ + c + 4);
        #pragma unroll
        for (int j = 0; j < 4; ++j) { o[j] = (__bf16)v0[j]; o[j + 4] = (__bf16)v1[j]; }
    } else {
        #pragma unroll
        for (int j = 0; j < 8; ++j) o[j] = (__bf16)0.f;
    }
    *(bf16x8*)(XB + (size_t)row * DIN_ + cs) = o;
}

// ---------------- weight prep: transpose + bf16 + swizzle ----------------
__global__ __launch_bounds__(256)
void prep_w1(const float* __restrict__ W1l, const float* __restrict__ W1r,
             const float* __restrict__ resW, __bf16* __restrict__ WT1)
{
    int idx = blockIdx.x * 256 + threadIdx.x;       // DIN_ * 192 threads
    if (idx >= DIN_ * 192) return;
    int k = idx / 192;
    int n0 = (idx - k * 192) * 4;
    const float* src; int col;
    if (n0 < 256)      { src = W1l;  col = n0; }
    else if (n0 < 512) { src = W1r;  col = n0 - 256; }
    else               { src = resW; col = n0 - 512; }
    f32x4 v = *(const f32x4*)(src + (size_t)k * DOUT_ + col);
    #pragma unroll
    for (int j = 0; j < 4; ++j) {
        int n = n0 + j;
        WT1[(size_t)n * DIN_ + swz_col(k, n)] = (__bf16)v[j];
    }
}

__global__ __launch_bounds__(256)
void prep_w2(const float* __restrict__ W2l, const float* __restrict__ W2r,
             __bf16* __restrict__ WT2)
{
    int idx = blockIdx.x * 256 + threadIdx.x;       // 256 * 128 threads
    if (idx >= 256 * 128) return;
    int k = idx / 128;
    int n0 = (idx - k * 128) * 4;
    const float* src; int col;
    if (n0 < 256) { src = W2l; col = n0; }
    else          { src = W2r; col = n0 - 256; }
    f32x4 v = *(const f32x4*)(src + (size_t)k * DOUT_ + col);
    #pragma unroll
    for (int j = 0; j < 4; ++j) {
        int n = n0 + j;
        WT2[(size_t)n * DOUT_ + swz_col(k, n)] = (__bf16)v[j];
    }
}

__global__ void prep_bias(const float* b1l, const float* b1r, const float* resb,
                          const float* b2l, const float* b2r,
                          float* B1, float* B2)
{
    int t = threadIdx.x;
    if (t < 256)      B1[t] = b1l[t];
    else if (t < 512) B1[t] = b1r[t - 256];
    else if (t < 768) B1[t] = resb[t - 512];
    if (t < 256)      B2[t] = b2l[t];
    else if (t < 512) B2[t] = b2r[t - 256];
}

// ---------------- CSR build ----------------
__global__ void init_deg(int* deg)
{
    int i = blockIdx.x * 256 + threadIdx.x;
    if (i < P_NODES) deg[i] = 1;                    // self loop
}

__global__ void hist_kernel(const int* __restrict__ dst, int* __restrict__ deg)
{
    int e = blockIdx.x * 256 + threadIdx.x;
    if (e < E_EDGES) atomicAdd(&deg[dst[e]], 1);
}

__global__ __launch_bounds__(1024)
void scan_kernel(const int* __restrict__ deg, int* __restrict__ offs, int* __restrict__ pos)
{
    __shared__ int sb[1024];
    const int t = threadIdx.x;
    const int base = t * 30;
    int ldv[30];
    int lsum = 0;
    #pragma unroll
    for (int i = 0; i < 30; ++i) {
        int idx = base + i;
        int v = (idx < P_NODES) ? deg[idx] : 0;
        ldv[i] = v; lsum += v;
    }
    sb[t] = lsum; __syncthreads();
    for (int off = 1; off < 1024; off <<= 1) {
        int v = (t >= off) ? sb[t - off] : 0;
        __syncthreads();
        sb[t] += v;
        __syncthreads();
    }
    int excl = sb[t] - lsum;
    #pragma unroll
    for (int i = 0; i < 30; ++i) {
        int idx = base + i;
        if (idx < P_NODES) { offs[idx] = excl; pos[idx] = excl; excl += ldv[i]; }
    }
    if (t == 0) offs[P_NODES] = ET;
}

__global__ void scatter_kernel(const int* __restrict__ ei, int* __restrict__ pos,
                               int* __restrict__ srcs)
{
    int tgt = blockIdx.x * 256 + threadIdx.x;
    if (tgt < E_EDGES) {
        int s = ei[tgt];
        int d = ei[E_EDGES + tgt];
        int p = atomicAdd(&pos[d], 1);
        srcs[p] = s;
    } else if (tgt < ET) {
        int i = tgt - E_EDGES;
        int p = atomicAdd(&pos[i], 1);
        srcs[p] = i;                                 // self loop
    }
}

// ---------------- bf16 MFMA GEMM ----------------
// C[M][N] = A[M][K] @ WT[N][K]^T + bias.  A, WT stored column-swizzled (swz_col).
// 128x128 tile, BK=64, 4 waves (2x2), global_load_lds width-16 staging,
// linear LDS dest + swizzled source => conflict-free ds_read_b128.
// EPI 0: cols<512 -> bf16 Cb[row*512+col], cols>=512 -> f32 Cf[row*256+col-512]
// EPI 1: all cols -> bf16 Cb[row*512+col]
template<int EPI>
__global__ __launch_bounds__(256)
void gemm_kernel(const __bf16* __restrict__ A, const __bf16* __restrict__ WT,
                 const float* __restrict__ bias,
                 __bf16* __restrict__ Cb, float* __restrict__ Cf,
                 int M, int N, int K, int ntiles)
{
    __shared__ __align__(16) __bf16 As[128 * 64];
    __shared__ __align__(16) __bf16 Bs[128 * 64];

    const int bid = blockIdx.x;
    const int mt = bid / ntiles, nt = bid - mt * ntiles;
    const int grow = mt * 128, gcol = nt * 128;
    const int t = threadIdx.x;
    const int lane = t & 63, wave = t >> 6;
    const int wr = wave >> 1, wc = wave & 1;
    const int fr = lane & 15, kg = lane >> 4;
    const int frs = fr & 7;

    // staging addresses: call i covers rows i*32 + t/8, granule t&7
    const __bf16* agp = A  + (size_t)(grow + (t >> 3)) * K + (t & 7) * 8;
    const __bf16* bgp = WT + (size_t)(gcol + (t >> 3)) * K + (t & 7) * 8;
    const size_t rstep = (size_t)32 * K;
    char* lA = (char*)As + wave * 1024;
    char* lB = (char*)Bs + wave * 1024;

    f32x4 acc[4][4] = {};

    for (int k0 = 0; k0 < K; k0 += 64) {
        __syncthreads();   // previous iteration's LDS reads complete
        #pragma unroll
        for (int i = 0; i < 4; ++i) {
            __builtin_amdgcn_global_load_lds(
                (const __attribute__((address_space(1))) void*)(agp + i * rstep + k0),
                (__attribute__((address_space(3))) void*)(lA + i * 4096), 16, 0, 0);
            __builtin_amdgcn_global_load_lds(
                (const __attribute__((address_space(1))) void*)(bgp + i * rstep + k0),
                (__attribute__((address_space(3))) void*)(lB + i * 4096), 16, 0, 0);
        }
        __syncthreads();   // vmcnt drained -> LDS ready

        #pragma unroll
        for (int ks = 0; ks < 2; ++ks) {
            bf16x8 af[4], bv[4];
            #pragma unroll
            for (int mi = 0; mi < 4; ++mi)
                af[mi] = *(const bf16x8*)&As[(wr * 64 + mi * 16 + fr) * 64 + (((ks * 4 + kg) ^ frs)) * 8];
            #pragma unroll
            for (int ni = 0; ni < 4; ++ni)
                bv[ni] = *(const bf16x8*)&Bs[(wc * 64 + ni * 16 + fr) * 64 + (((ks * 4 + kg) ^ frs)) * 8];
            #pragma unroll
            for (int mi = 0; mi < 4; ++mi)
                #pragma unroll
                for (int ni = 0; ni < 4; ++ni)
                    acc[mi][ni] = __builtin_amdgcn_mfma_f32_16x16x32_bf16(af[mi], bv[ni], acc[mi][ni], 0, 0, 0);
        }
    }

    #pragma unroll
    for (int mi = 0; mi < 4; ++mi) {
        #pragma unroll
        for (int ni = 0; ni < 4; ++ni) {
            int col = gcol + wc * 64 + ni * 16 + fr;
            float bvv = bias[col];
            #pragma unroll
            for (int j = 0; j < 4; ++j) {
                int row = grow + wr * 64 + mi * 16 + kg * 4 + j;
                if (row < M) {
                    float v = acc[mi][ni][j] + bvv;
                    if (EPI == 0) {
                        if (col < 512) Cb[(size_t)row * 512 + col] = (__bf16)v;
                        else           Cf[(size_t)row * 256 + col - 512] = v;
                    } else {
                        Cb[(size_t)row * 512 + col] = (__bf16)v;
                    }
                }
            }
        }
    }
}

// ---------------- GATv2 edge aggregation: one wave per destination node ----------------
// XLXR: bf16 [P][512], xl at 0..255, xr at 256..511 (unswizzled)
__global__ __launch_bounds__(256)
void gat_kernel(const __bf16* __restrict__ XLXR,
                const int* __restrict__ offs, const int* __restrict__ srcs,
                const float* __restrict__ att, const float* __restrict__ bias,
                float* __restrict__ out)
{
    const int node = blockIdx.x * 4 + (threadIdx.x >> 6);
    const int lane = threadIdx.x & 63;
    const int c0 = lane * 4;                        // lanes 0-31: head0, 32-63: head1
    bf16x4 xrb = *(const bf16x4*)(XLXR + (size_t)node * 512 + 256 + c0);
    f32x4 xr, at = *(const f32x4*)(att + c0);
    #pragma unroll
    for (int j = 0; j < 4; ++j) xr[j] = (float)xrb[j];
    f32x4 acc = {0.f, 0.f, 0.f, 0.f};
    float m = -INFINITY, den = 0.f;
    const int e1 = offs[node + 1];
    for (int e = offs[node]; e < e1; ++e) {
        int s = srcs[e];
        bf16x4 xlb = *(const bf16x4*)(XLXR + (size_t)s * 512 + c0);
        f32x4 xl;
        float p = 0.f;
        #pragma unroll
        for (int j = 0; j < 4; ++j) {
            xl[j] = (float)xlb[j];
            float tt = xl[j] + xr[j];
            float lr = tt > 0.f ? tt : NEG * tt;
            p = fmaf(at[j], lr, p);
        }
        #pragma unroll
        for (int w = 1; w < 32; w <<= 1) p += __shfl_xor(p, w, 32);
        float nm = fmaxf(m, p);
        float sc = __expf(m - nm);                  // m = -inf -> 0
        float wv = __expf(p - nm);
        den = den * sc + wv;
        #pragma unroll
        for (int j = 0; j < 4; ++j) acc[j] = acc[j] * sc + wv * xl[j];
        m = nm;
    }
    float inv = 1.f / den;
    f32x4 o;
    #pragma unroll
    for (int j = 0; j < 4; ++j) o[j] = acc[j] * inv + bias[c0 + j];
    *(f32x4*)(out + (size_t)node * DOUT_ + c0) = o;
}

// ---------------- h1 = elu(LN(gat1)) + res ; bf16 swizzled copy for GEMM2 ----------------
__global__ __launch_bounds__(256)
void h1_kernel(const float* __restrict__ GAT, const float* __restrict__ RES,
               const float* __restrict__ g, const float* __restrict__ b,
               float* __restrict__ H1, __bf16* __restrict__ H1B)
{
    const int node = blockIdx.x * 4 + (threadIdx.x >> 6);   // grid covers P_PAD
    const int lane = threadIdx.x & 63;
    const int c0 = lane * 4;
    const int cs = swz_col(c0, node);
    if (node >= P_NODES) {                          // zero-pad rows for GEMM2 staging
        bf16x4 z; 
        #pragma unroll
        for (int j = 0; j < 4; ++j) z[j] = (__bf16)0.f;
        *(bf16x4*)(H1B + (size_t)node * DOUT_ + cs) = z;
        return;
    }
    f32x4 h = *(const f32x4*)(GAT + (size_t)node * DOUT_ + c0);
    float s = h[0] + h[1] + h[2] + h[3];
    #pragma unroll
    for (int w = 1; w < 64; w <<= 1) s += __shfl_xor(s, w, 64);
    float mu = s * (1.f / DOUT_);
    f32x4 d; float sq = 0.f;
    #pragma unroll
    for (int j = 0; j < 4; ++j) { d[j] = h[j] - mu; sq += d[j] * d[j]; }
    #pragma unroll
    for (int w = 1; w < 64; w <<= 1) sq += __shfl_xor(sq, w, 64);
    float rs = rsqrtf(sq * (1.f / DOUT_) + 1e-5f);
    f32x4 res = *(const f32x4*)(RES + (size_t)node * DOUT_ + c0);
    f32x4 o; bf16x4 hb;
    #pragma unroll
    for (int j = 0; j < 4; ++j) {
        float y = d[j] * rs * g[c0 + j] + b[c0 + j];
        float e = y > 0.f ? y : __expf(y) - 1.f;
        o[j] = e + res[j];
        hb[j] = (__bf16)o[j];
    }
    *(f32x4*)(H1 + (size_t)node * DOUT_ + c0) = o;
    *(bf16x4*)(H1B + (size_t)node * DOUT_ + cs) = hb;
}

// ---------------- out = max(h1, elu(LN(gat2)) + h1) ----------------
__global__ __launch_bounds__(256)
void final_kernel(const float* __restrict__ GAT2, const float* __restrict__ H1,
                  const float* __restrict__ g, const float* __restrict__ b,
                  float* __restrict__ out)
{
    const int node = blockIdx.x * 4 + (threadIdx.x >> 6);
    const int lane = threadIdx.x & 63;
    const int c0 = lane * 4;
    f32x4 h = *(const f32x4*)(GAT2 + (size_t)node * DOUT_ + c0);
    float s = h[0] + h[1] + h[2] + h[3];
    #pragma unroll
    for (int w = 1; w < 64; w <<= 1) s += __shfl_xor(s, w, 64);
    float mu = s * (1.f / DOUT_);
    f32x4 d; float sq = 0.f;
    #pragma unroll
    for (int j = 0; j < 4; ++j) { d[j] = h[j] - mu; sq += d[j] * d[j]; }
    #pragma unroll
    for (int w = 1; w < 64; w <<= 1) sq += __shfl_xor(sq, w, 64);
    float rs = rsqrtf(sq * (1.f / DOUT_) + 1e-5f);
    f32x4 h1v = *(const f32x4*)(H1 + (size_t)node * DOUT_ + c0);
    f32x4 o;
    #pragma unroll
    for (int j = 0; j < 4; ++j) {
        float y = d[j] * rs * g[c0 + j] + b[c0 + j];
        float e = y > 0.f ? y : __expf(y) - 1.f;
        float h2 = e + h1v[j];
        o[j] = fmaxf(h1v[j], h2);
    }
    *(f32x4*)(out + (size_t)node * DOUT_ + c0) = o;
}

// ---------------- launch ----------------
extern "C" void kernel_launch(void* const* d_in, const int* in_sizes, int n_in,
                              void* d_out, int out_size, void* d_ws, size_t ws_size,
                              hipStream_t stream)
{
    const float* x     = (const float*)d_in[0];
    const int*   ei    = (const int*)d_in[1];
    const float* W1l   = (const float*)d_in[2];
    const float* b1l   = (const float*)d_in[3];
    const float* W1r   = (const float*)d_in[4];
    const float* b1r   = (const float*)d_in[5];
    const float* att1  = (const float*)d_in[6];
    const float* bias1 = (const float*)d_in[7];
    const float* W2l   = (const float*)d_in[8];
    const float* b2l   = (const float*)d_in[9];
    const float* W2r   = (const float*)d_in[10];
    const float* b2r   = (const float*)d_in[11];
    const float* att2  = (const float*)d_in[12];
    const float* bias2 = (const float*)d_in[13];
    const float* ln1g  = (const float*)d_in[14];
    const float* ln1b  = (const float*)d_in[15];
    const float* ln2g  = (const float*)d_in[16];
    const float* ln2b  = (const float*)d_in[17];
    const float* resW  = (const float*)d_in[18];
    const float* resb  = (const float*)d_in[19];
    float* out = (float*)d_out;

    char* w = (char*)d_ws;
    auto alloc = [&](size_t bytes) {
        char* r = w;
        w += (bytes + 255) & ~(size_t)255;
        return r;
    };
    __bf16* XB    = (__bf16*)alloc((size_t)P_PAD * DIN_ * 2);     // 92.4 MB (dead after GEMM1)
    __bf16* XLR1  = (__bf16*)alloc((size_t)P_NODES * 512 * 2);    // xl|xr layer1, bf16
    float*  RES   = (float*)alloc((size_t)P_NODES * 256 * 4);     // x @ resW
    float*  H1    = (float*)alloc((size_t)P_NODES * 256 * 4);
    __bf16* WT1   = (__bf16*)alloc((size_t)768 * DIN_ * 2);
    __bf16* WT2   = (__bf16*)alloc((size_t)512 * DOUT_ * 2);
    float*  BIAS1 = (float*)alloc(768 * 4);
    float*  BIAS2 = (float*)alloc(512 * 4);
    int*    deg   = (int*)alloc((size_t)P_NODES * 4);
    int*    offs  = (int*)alloc((size_t)(P_NODES + 1) * 4);
    int*    pos   = (int*)alloc((size_t)(P_NODES + 1) * 4);
    int*    srcs  = (int*)alloc((size_t)ET * 4);

    // aliases into XB (XB only live through GEMM1; these only live after it)
    __bf16* XLR2 = (__bf16*)XB;                                   // [0, 30.7MB)
    __bf16* H1B  = (__bf16*)((char*)XB + (size_t)32 * 1024 * 1024);   // [32, 47.4MB)
    float*  GAT  = (float*)((char*)XB + (size_t)48 * 1024 * 1024);    // [48, 78.7MB)

    // prep + CSR build
    cast_x<<<(P_PAD * 192 + 255) / 256, 256, 0, stream>>>(x, XB);
    prep_w1<<<(DIN_ * 192 + 255) / 256, 256, 0, stream>>>(W1l, W1r, resW, WT1);
    prep_w2<<<(256 * 128 + 255) / 256, 256, 0, stream>>>(W2l, W2r, WT2);
    prep_bias<<<1, 1024, 0, stream>>>(b1l, b1r, resb, b2l, b2r, BIAS1, BIAS2);
    init_deg<<<(P_NODES + 255) / 256, 256, 0, stream>>>(deg);
    hist_kernel<<<(E_EDGES + 255) / 256, 256, 0, stream>>>(ei + E_EDGES, deg);
    scan_kernel<<<1, 1024, 0, stream>>>(deg, offs, pos);
    scatter_kernel<<<(ET + 255) / 256, 256, 0, stream>>>(ei, pos, srcs);

    const int mtiles = P_PAD / 128;   // 235

    // layer 1
    gemm_kernel<0><<<mtiles * 6, 256, 0, stream>>>(XB, WT1, BIAS1, XLR1, RES, P_NODES, 768, DIN_, 6);
    gat_kernel<<<P_NODES / 4, 256, 0, stream>>>(XLR1, offs, srcs, att1, bias1, GAT);
    h1_kernel<<<P_PAD / 4, 256, 0, stream>>>(GAT, RES, ln1g, ln1b, H1, H1B);

    // layer 2
    gemm_kernel<1><<<mtiles * 4, 256, 0, stream>>>(H1B, WT2, BIAS2, XLR2, nullptr, P_NODES, 512, DOUT_, 4);
    gat_kernel<<<P_NODES / 4, 256, 0, stream>>>(XLR2, offs, srcs, att2, bias2, GAT);
    final_kernel<<<P_NODES / 4, 256, 0, stream>>>(GAT, H1, ln2g, ln2b, out);
}

// Round 4
// 653.587 us; speedup vs baseline: 1.1211x; 1.0093x over previous
//
#include <hip/hip_runtime.h>
#include <math.h>

#define P_NODES 30000
#define P_PAD   30080          // 235 * 128
#define DIN_    1536
#define DOUT_   256
#define E_EDGES 320000
#define ET      (E_EDGES + P_NODES)
#define NEG     0.2f
#define BIG_NEG (-1e30f)

typedef float  f32x4  __attribute__((ext_vector_type(4)));
typedef __bf16 bf16x8 __attribute__((ext_vector_type(8)));
typedef __bf16 bf16x4 __attribute__((ext_vector_type(4)));

// swizzled column for storage feeding global_load_lds-staged GEMM A/B:
// within each 64-col chunk, 16B granule g goes to position g ^ (row & 7)
__device__ __forceinline__ int swz_col(int c, int row) {
    return (c & ~63) | ((((c >> 3) ^ row) & 7) << 3) | (c & 7);
}

// bijective XCD-chunking swizzle (m204): contiguous wgid chunks per XCD
__device__ __forceinline__ int xcd_swz(int orig, int nwg) {
    int q = nwg >> 3, r = nwg & 7;
    int xcd = orig & 7, idx = orig >> 3;
    return (xcd < r ? xcd * (q + 1) : r * (q + 1) + (xcd - r) * q) + idx;
}

// ---------------- x -> bf16, pre-swizzled, rows padded to P_PAD ----------------
__global__ __launch_bounds__(256)
void cast_x(const float* __restrict__ x, __bf16* __restrict__ XB)
{
    int idx = blockIdx.x * 256 + threadIdx.x;      // P_PAD * 192
    if (idx >= P_PAD * 192) return;
    int row = idx / 192;
    int c = (idx - row * 192) * 8;
    int cs = swz_col(c, row);
    bf16x8 o;
    if (row < P_NODES) {
        f32x4 v0 = *(const f32x4*)(x + (size_t)row * DIN_ + c);
        f32x4 v1 = *(const f32x4*)(x + (size_t)row * DIN_ + c + 4);
        #pragma unroll
        for (int j = 0; j < 4; ++j) { o[j] = (__bf16)v0[j]; o[j + 4] = (__bf16)v1[j]; }
    } else {
        #pragma unroll
        for (int j = 0; j < 8; ++j) o[j] = (__bf16)0.f;
    }
    *(bf16x8*)(XB + (size_t)row * DIN_ + cs) = o;
}

// ---------------- weight prep: transpose + bf16 + swizzle ----------------
__global__ __launch_bounds__(256)
void prep_w1(const float* __restrict__ W1l, const float* __restrict__ W1r,
             const float* __restrict__ resW, __bf16* __restrict__ WT1)
{
    int idx = blockIdx.x * 256 + threadIdx.x;       // DIN_ * 192 threads
    if (idx >= DIN_ * 192) return;
    int k = idx / 192;
    int n0 = (idx - k * 192) * 4;
    const float* src; int col;
    if (n0 < 256)      { src = W1l;  col = n0; }
    else if (n0 < 512) { src = W1r;  col = n0 - 256; }
    else               { src = resW; col = n0 - 512; }
    f32x4 v = *(const f32x4*)(src + (size_t)k * DOUT_ + col);
    #pragma unroll
    for (int j = 0; j < 4; ++j) {
        int n = n0 + j;
        WT1[(size_t)n * DIN_ + swz_col(k, n)] = (__bf16)v[j];
    }
}

__global__ __launch_bounds__(256)
void prep_w2(const float* __restrict__ W2l, const float* __restrict__ W2r,
             __bf16* __restrict__ WT2)
{
    int idx = blockIdx.x * 256 + threadIdx.x;       // 256 * 128 threads
    if (idx >= 256 * 128) return;
    int k = idx / 128;
    int n0 = (idx - k * 128) * 4;
    const float* src; int col;
    if (n0 < 256) { src = W2l; col = n0; }
    else          { src = W2r; col = n0 - 256; }
    f32x4 v = *(const f32x4*)(src + (size_t)k * DOUT_ + col);
    #pragma unroll
    for (int j = 0; j < 4; ++j) {
        int n = n0 + j;
        WT2[(size_t)n * DOUT_ + swz_col(k, n)] = (__bf16)v[j];
    }
}

__global__ void prep_bias(const float* b1l, const float* b1r, const float* resb,
                          const float* b2l, const float* b2r,
                          float* B1, float* B2)
{
    int t = threadIdx.x;
    if (t < 256)      B1[t] = b1l[t];
    else if (t < 512) B1[t] = b1r[t - 256];
    else if (t < 768) B1[t] = resb[t - 512];
    if (t < 256)      B2[t] = b2l[t];
    else if (t < 512) B2[t] = b2r[t - 256];
}

// ---------------- CSR build ----------------
__global__ void init_deg(int* deg)
{
    int i = blockIdx.x * 256 + threadIdx.x;
    if (i < P_NODES) deg[i] = 1;                    // self loop
}

__global__ void hist_kernel(const int* __restrict__ dst, int* __restrict__ deg)
{
    int e = blockIdx.x * 256 + threadIdx.x;
    if (e < E_EDGES) atomicAdd(&deg[dst[e]], 1);
}

__global__ __launch_bounds__(1024)
void scan_kernel(const int* __restrict__ deg, int* __restrict__ offs, int* __restrict__ pos)
{
    __shared__ int sb[1024];
    const int t = threadIdx.x;
    const int base = t * 30;
    int ldv[30];
    int lsum = 0;
    #pragma unroll
    for (int i = 0; i < 30; ++i) {
        int idx = base + i;
        int v = (idx < P_NODES) ? deg[idx] : 0;
        ldv[i] = v; lsum += v;
    }
    sb[t] = lsum; __syncthreads();
    for (int off = 1; off < 1024; off <<= 1) {
        int v = (t >= off) ? sb[t - off] : 0;
        __syncthreads();
        sb[t] += v;
        __syncthreads();
    }
    int excl = sb[t] - lsum;
    #pragma unroll
    for (int i = 0; i < 30; ++i) {
        int idx = base + i;
        if (idx < P_NODES) { offs[idx] = excl; pos[idx] = excl; excl += ldv[i]; }
    }
    if (t == 0) offs[P_NODES] = ET;
}

__global__ void scatter_kernel(const int* __restrict__ ei, int* __restrict__ pos,
                               int* __restrict__ srcs)
{
    int tgt = blockIdx.x * 256 + threadIdx.x;
    if (tgt < E_EDGES) {
        int s = ei[tgt];
        int d = ei[E_EDGES + tgt];
        int p = atomicAdd(&pos[d], 1);
        srcs[p] = s;
    } else if (tgt < ET) {
        int i = tgt - E_EDGES;
        int p = atomicAdd(&pos[i], 1);
        srcs[p] = i;                                 // self loop
    }
}

// ---------------- bf16 MFMA GEMM ----------------
// C[M][N] = A[M][K] @ WT[N][K]^T + bias.  A, WT stored column-swizzled (swz_col).
// 128x128 tile, BK=64, 4 waves (2x2), global_load_lds width-16 staging,
// linear LDS dest + swizzled source => conflict-free ds_read_b128.
// XCD-chunked block swizzle for A-panel L2 locality.
// EPI 0: cols<512 -> bf16 Cb[row*512+col], cols>=512 -> f32 Cf[row*256+col-512]
// EPI 1: all cols -> bf16 Cb[row*512+col]
template<int EPI>
__global__ __launch_bounds__(256)
void gemm_kernel(const __bf16* __restrict__ A, const __bf16* __restrict__ WT,
                 const float* __restrict__ bias,
                 __bf16* __restrict__ Cb, float* __restrict__ Cf,
                 int M, int N, int K, int ntiles)
{
    __shared__ __align__(16) __bf16 As[128 * 64];
    __shared__ __align__(16) __bf16 Bs[128 * 64];

    const int bid = xcd_swz(blockIdx.x, gridDim.x);
    const int mt = bid / ntiles, nt = bid - mt * ntiles;
    const int grow = mt * 128, gcol = nt * 128;
    const int t = threadIdx.x;
    const int lane = t & 63, wave = t >> 6;
    const int wr = wave >> 1, wc = wave & 1;
    const int fr = lane & 15, kg = lane >> 4;
    const int frs = fr & 7;

    // staging addresses: call i covers rows i*32 + t/8, granule t&7
    const __bf16* agp = A  + (size_t)(grow + (t >> 3)) * K + (t & 7) * 8;
    const __bf16* bgp = WT + (size_t)(gcol + (t >> 3)) * K + (t & 7) * 8;
    const size_t rstep = (size_t)32 * K;
    char* lA = (char*)As + wave * 1024;
    char* lB = (char*)Bs + wave * 1024;

    f32x4 acc[4][4] = {};

    for (int k0 = 0; k0 < K; k0 += 64) {
        __syncthreads();   // previous iteration's LDS reads complete
        #pragma unroll
        for (int i = 0; i < 4; ++i) {
            __builtin_amdgcn_global_load_lds(
                (const __attribute__((address_space(1))) void*)(agp + i * rstep + k0),
                (__attribute__((address_space(3))) void*)(lA + i * 4096), 16, 0, 0);
            __builtin_amdgcn_global_load_lds(
                (const __attribute__((address_space(1))) void*)(bgp + i * rstep + k0),
                (__attribute__((address_space(3))) void*)(lB + i * 4096), 16, 0, 0);
        }
        __syncthreads();   // vmcnt drained -> LDS ready

        #pragma unroll
        for (int ks = 0; ks < 2; ++ks) {
            bf16x8 af[4], bv[4];
            #pragma unroll
            for (int mi = 0; mi < 4; ++mi)
                af[mi] = *(const bf16x8*)&As[(wr * 64 + mi * 16 + fr) * 64 + (((ks * 4 + kg) ^ frs)) * 8];
            #pragma unroll
            for (int ni = 0; ni < 4; ++ni)
                bv[ni] = *(const bf16x8*)&Bs[(wc * 64 + ni * 16 + fr) * 64 + (((ks * 4 + kg) ^ frs)) * 8];
            #pragma unroll
            for (int mi = 0; mi < 4; ++mi)
                #pragma unroll
                for (int ni = 0; ni < 4; ++ni)
                    acc[mi][ni] = __builtin_amdgcn_mfma_f32_16x16x32_bf16(af[mi], bv[ni], acc[mi][ni], 0, 0, 0);
        }
    }

    #pragma unroll
    for (int mi = 0; mi < 4; ++mi) {
        #pragma unroll
        for (int ni = 0; ni < 4; ++ni) {
            int col = gcol + wc * 64 + ni * 16 + fr;
            float bvv = bias[col];
            #pragma unroll
            for (int j = 0; j < 4; ++j) {
                int row = grow + wr * 64 + mi * 16 + kg * 4 + j;
                if (row < M) {
                    float v = acc[mi][ni][j] + bvv;
                    if (EPI == 0) {
                        if (col < 512) Cb[(size_t)row * 512 + col] = (__bf16)v;
                        else           Cf[(size_t)row * 256 + col - 512] = v;
                    } else {
                        Cb[(size_t)row * 512 + col] = (__bf16)v;
                    }
                }
            }
        }
    }
}

// ---------------- fused GATv2 + LN + ELU + residual / JK-max ----------------
// One wave per node; 4 groups x 16 lanes; group g handles edges eb+g.
// Lane l holds channels [l*8, l*8+8) of head0 and [128+l*8, ...+8) of head1.
// LAYER 1: OutF=H1 (f32), OutB=H1B (bf16, swz_col), AUX=RES (f32)
// LAYER 2: OutF=out (f32), AUX=H1 (f32)
template<int LAYER>
__global__ __launch_bounds__(256)
void gat_fused(const __bf16* __restrict__ XLXR,
               const int* __restrict__ offs, const int* __restrict__ srcs,
               const float* __restrict__ att, const float* __restrict__ bias,
               const float* __restrict__ lng, const float* __restrict__ lnb,
               const float* __restrict__ AUX,
               float* __restrict__ OutF, __bf16* __restrict__ OutB)
{
    const int node = blockIdx.x * 4 + (threadIdx.x >> 6);
    const int lane = threadIdx.x & 63;
    const int grp = lane >> 4, l = lane & 15;
    const int ch0 = l * 8, ch1 = 128 + l * 8;

    bf16x8 xr0b = *(const bf16x8*)(XLXR + (size_t)node * 512 + 256 + ch0);
    bf16x8 xr1b = *(const bf16x8*)(XLXR + (size_t)node * 512 + 256 + ch1);
    float xr0[8], xr1[8], at0[8], at1[8];
    #pragma unroll
    for (int j = 0; j < 8; ++j) { xr0[j] = (float)xr0b[j]; xr1[j] = (float)xr1b[j]; }
    *(f32x4*)(at0)     = *(const f32x4*)(att + ch0);
    *(f32x4*)(at0 + 4) = *(const f32x4*)(att + ch0 + 4);
    *(f32x4*)(at1)     = *(const f32x4*)(att + ch1);
    *(f32x4*)(at1 + 4) = *(const f32x4*)(att + ch1 + 4);

    float m0 = BIG_NEG, m1 = BIG_NEG, den0 = 0.f, den1 = 0.f;
    float acc0[8] = {}, acc1[8] = {};

    const int e0 = offs[node], e1 = offs[node + 1];
    for (int eb = e0; eb < e1; eb += 4) {
        int e = eb + grp;
        bool valid = e < e1;
        int ee = valid ? e : e1 - 1;
        int s = srcs[ee];
        const __bf16* xp = XLXR + (size_t)s * 512;
        bf16x8 a0 = *(const bf16x8*)(xp + ch0);
        bf16x8 a1 = *(const bf16x8*)(xp + ch1);
        float xl0[8], xl1[8];
        float p0 = 0.f, p1 = 0.f;
        #pragma unroll
        for (int j = 0; j < 8; ++j) {
            xl0[j] = (float)a0[j];
            float tt = xl0[j] + xr0[j];
            float lr = tt > 0.f ? tt : NEG * tt;
            p0 = fmaf(at0[j], lr, p0);
            xl1[j] = (float)a1[j];
            float t1 = xl1[j] + xr1[j];
            float l1 = t1 > 0.f ? t1 : NEG * t1;
            p1 = fmaf(at1[j], l1, p1);
        }
        #pragma unroll
        for (int w = 1; w < 16; w <<= 1) {
            p0 += __shfl_xor(p0, w);
            p1 += __shfl_xor(p1, w);
        }
        if (!valid) { p0 = BIG_NEG; p1 = BIG_NEG; }
        // online-softmax update (group-local chain)
        float nm0 = fmaxf(m0, p0), nm1 = fmaxf(m1, p1);
        float sc0 = __expf(m0 - nm0), wv0 = __expf(p0 - nm0);
        float sc1 = __expf(m1 - nm1), wv1 = __expf(p1 - nm1);
        den0 = den0 * sc0 + wv0;
        den1 = den1 * sc1 + wv1;
        #pragma unroll
        for (int j = 0; j < 8; ++j) {
            acc0[j] = acc0[j] * sc0 + wv0 * xl0[j];
            acc1[j] = acc1[j] * sc1 + wv1 * xl1[j];
        }
        m0 = nm0; m1 = nm1;
    }

    // merge the 4 groups' online states (empty groups have m=BIG_NEG -> scale 0)
    #pragma unroll
    for (int w = 16; w <= 32; w <<= 1) {
        float mb0 = __shfl_xor(m0, w), db0 = __shfl_xor(den0, w);
        float mb1 = __shfl_xor(m1, w), db1 = __shfl_xor(den1, w);
        float M0 = fmaxf(m0, mb0), M1 = fmaxf(m1, mb1);
        float sa0 = __expf(m0 - M0), sb0 = __expf(mb0 - M0);
        float sa1 = __expf(m1 - M1), sb1 = __expf(mb1 - M1);
        den0 = den0 * sa0 + db0 * sb0;
        den1 = den1 * sa1 + db1 * sb1;
        #pragma unroll
        for (int j = 0; j < 8; ++j) {
            float ab0 = __shfl_xor(acc0[j], w);
            float ab1 = __shfl_xor(acc1[j], w);
            acc0[j] = acc0[j] * sa0 + ab0 * sb0;
            acc1[j] = acc1[j] * sa1 + ab1 * sb1;
        }
        m0 = M0; m1 = M1;
    }

    float inv0 = 1.f / den0, inv1 = 1.f / den1;
    float o0[8], o1[8];
    #pragma unroll
    for (int j = 0; j < 8; ++j) {
        o0[j] = acc0[j] * inv0 + bias[ch0 + j];
        o1[j] = acc1[j] * inv1 + bias[ch1 + j];
    }

    // LayerNorm over 256 channels (row replicated in each 16-lane group)
    float s = 0.f;
    #pragma unroll
    for (int j = 0; j < 8; ++j) s += o0[j] + o1[j];
    #pragma unroll
    for (int w = 1; w < 16; w <<= 1) s += __shfl_xor(s, w);
    float mu = s * (1.f / 256.f);
    float sq = 0.f;
    #pragma unroll
    for (int j = 0; j < 8; ++j) {
        o0[j] -= mu; o1[j] -= mu;
        sq += o0[j] * o0[j] + o1[j] * o1[j];
    }
    #pragma unroll
    for (int w = 1; w < 16; w <<= 1) sq += __shfl_xor(sq, w);
    float rs = rsqrtf(sq * (1.f / 256.f) + 1e-5f);

    float g0[8], g1[8], bb0[8], bb1[8], x0[8], x1[8];
    *(f32x4*)(g0)      = *(const f32x4*)(lng + ch0);
    *(f32x4*)(g0 + 4)  = *(const f32x4*)(lng + ch0 + 4);
    *(f32x4*)(g1)      = *(const f32x4*)(lng + ch1);
    *(f32x4*)(g1 + 4)  = *(const f32x4*)(lng + ch1 + 4);
    *(f32x4*)(bb0)     = *(const f32x4*)(lnb + ch0);
    *(f32x4*)(bb0 + 4) = *(const f32x4*)(lnb + ch0 + 4);
    *(f32x4*)(bb1)     = *(const f32x4*)(lnb + ch1);
    *(f32x4*)(bb1 + 4) = *(const f32x4*)(lnb + ch1 + 4);
    *(f32x4*)(x0)      = *(const f32x4*)(AUX + (size_t)node * 256 + ch0);
    *(f32x4*)(x0 + 4)  = *(const f32x4*)(AUX + (size_t)node * 256 + ch0 + 4);
    *(f32x4*)(x1)      = *(const f32x4*)(AUX + (size_t)node * 256 + ch1);
    *(f32x4*)(x1 + 4)  = *(const f32x4*)(AUX + (size_t)node * 256 + ch1 + 4);

    float r0[8], r1[8];
    #pragma unroll
    for (int j = 0; j < 8; ++j) {
        float y0 = o0[j] * rs * g0[j] + bb0[j];
        float y1 = o1[j] * rs * g1[j] + bb1[j];
        float e0v = y0 > 0.f ? y0 : __expf(y0) - 1.f;
        float e1v = y1 > 0.f ? y1 : __expf(y1) - 1.f;
        if (LAYER == 1) {
            r0[j] = e0v + x0[j];            // h1 = elu(LN(gat1)) + res
            r1[j] = e1v + x1[j];
        } else {
            float h20 = e0v + x0[j];        // h2 = elu(LN(gat2)) + h1
            float h21 = e1v + x1[j];
            r0[j] = fmaxf(x0[j], h20);      // JK max
            r1[j] = fmaxf(x1[j], h21);
        }
    }

    if (grp == 0) {
        float* op = OutF + (size_t)node * 256;
        *(f32x4*)(op + ch0)     = *(f32x4*)(r0);
        *(f32x4*)(op + ch0 + 4) = *(f32x4*)(r0 + 4);
        *(f32x4*)(op + ch1)     = *(f32x4*)(r1);
        *(f32x4*)(op + ch1 + 4) = *(f32x4*)(r1 + 4);
        if (LAYER == 1) {
            bf16x8 hb0, hb1;
            #pragma unroll
            for (int j = 0; j < 8; ++j) { hb0[j] = (__bf16)r0[j]; hb1[j] = (__bf16)r1[j]; }
            *(bf16x8*)(OutB + (size_t)node * 256 + swz_col(ch0, node)) = hb0;
            *(bf16x8*)(OutB + (size_t)node * 256 + swz_col(ch1, node)) = hb1;
        }
    }
}

// zero-pad H1B rows [P_NODES, P_PAD) for GEMM2 staging
__global__ void pad_h1b(__bf16* __restrict__ H1B)
{
    int i = blockIdx.x * 256 + threadIdx.x;     // (P_PAD-P_NODES)*32 granules
    if (i >= (P_PAD - P_NODES) * 32) return;
    int row = P_NODES + (i >> 5);
    int c = (i & 31) * 8;
    bf16x8 z;
    #pragma unroll
    for (int j = 0; j < 8; ++j) z[j] = (__bf16)0.f;
    *(bf16x8*)(H1B + (size_t)row * 256 + c) = z;
}

// ---------------- launch ----------------
extern "C" void kernel_launch(void* const* d_in, const int* in_sizes, int n_in,
                              void* d_out, int out_size, void* d_ws, size_t ws_size,
                              hipStream_t stream)
{
    const float* x     = (const float*)d_in[0];
    const int*   ei    = (const int*)d_in[1];
    const float* W1l   = (const float*)d_in[2];
    const float* b1l   = (const float*)d_in[3];
    const float* W1r   = (const float*)d_in[4];
    const float* b1r   = (const float*)d_in[5];
    const float* att1  = (const float*)d_in[6];
    const float* bias1 = (const float*)d_in[7];
    const float* W2l   = (const float*)d_in[8];
    const float* b2l   = (const float*)d_in[9];
    const float* W2r   = (const float*)d_in[10];
    const float* b2r   = (const float*)d_in[11];
    const float* att2  = (const float*)d_in[12];
    const float* bias2 = (const float*)d_in[13];
    const float* ln1g  = (const float*)d_in[14];
    const float* ln1b  = (const float*)d_in[15];
    const float* ln2g  = (const float*)d_in[16];
    const float* ln2b  = (const float*)d_in[17];
    const float* resW  = (const float*)d_in[18];
    const float* resb  = (const float*)d_in[19];
    float* out = (float*)d_out;

    char* w = (char*)d_ws;
    auto alloc = [&](size_t bytes) {
        char* r = w;
        w += (bytes + 255) & ~(size_t)255;
        return r;
    };
    __bf16* XB    = (__bf16*)alloc((size_t)P_PAD * DIN_ * 2);     // 92.4 MB (dead after GEMM1)
    __bf16* XLR1  = (__bf16*)alloc((size_t)P_NODES * 512 * 2);    // xl|xr layer1, bf16
    float*  RES   = (float*)alloc((size_t)P_NODES * 256 * 4);     // x @ resW
    float*  H1    = (float*)alloc((size_t)P_NODES * 256 * 4);
    __bf16* WT1   = (__bf16*)alloc((size_t)768 * DIN_ * 2);
    __bf16* WT2   = (__bf16*)alloc((size_t)512 * DOUT_ * 2);
    float*  BIAS1 = (float*)alloc(768 * 4);
    float*  BIAS2 = (float*)alloc(512 * 4);
    int*    deg   = (int*)alloc((size_t)P_NODES * 4);
    int*    offs  = (int*)alloc((size_t)(P_NODES + 1) * 4);
    int*    pos   = (int*)alloc((size_t)(P_NODES + 1) * 4);
    int*    srcs  = (int*)alloc((size_t)ET * 4);

    // aliases into XB (XB only live through GEMM1; these only live after it)
    __bf16* XLR2 = (__bf16*)XB;                                       // [0, 30.7MB)
    __bf16* H1B  = (__bf16*)((char*)XB + (size_t)32 * 1024 * 1024);   // [32, 47.4MB)

    // prep + CSR build
    cast_x<<<(P_PAD * 192 + 255) / 256, 256, 0, stream>>>(x, XB);
    prep_w1<<<(DIN_ * 192 + 255) / 256, 256, 0, stream>>>(W1l, W1r, resW, WT1);
    prep_w2<<<(256 * 128 + 255) / 256, 256, 0, stream>>>(W2l, W2r, WT2);
    prep_bias<<<1, 1024, 0, stream>>>(b1l, b1r, resb, b2l, b2r, BIAS1, BIAS2);
    init_deg<<<(P_NODES + 255) / 256, 256, 0, stream>>>(deg);
    hist_kernel<<<(E_EDGES + 255) / 256, 256, 0, stream>>>(ei + E_EDGES, deg);
    scan_kernel<<<1, 1024, 0, stream>>>(deg, offs, pos);
    scatter_kernel<<<(ET + 255) / 256, 256, 0, stream>>>(ei, pos, srcs);

    const int mtiles = P_PAD / 128;   // 235

    // layer 1: GEMM -> fused GAT+LN+ELU+residual (writes H1 f32 + H1B bf16-swz)
    gemm_kernel<0><<<mtiles * 6, 256, 0, stream>>>(XB, WT1, BIAS1, XLR1, RES, P_NODES, 768, DIN_, 6);
    gat_fused<1><<<P_NODES / 4, 256, 0, stream>>>(XLR1, offs, srcs, att1, bias1,
                                                  ln1g, ln1b, RES, H1, H1B);
    pad_h1b<<<((P_PAD - P_NODES) * 32 + 255) / 256, 256, 0, stream>>>(H1B);

    // layer 2: GEMM -> fused GAT+LN+ELU+h1-residual+JK-max (writes out)
    gemm_kernel<1><<<mtiles * 4, 256, 0, stream>>>(H1B, WT2, BIAS2, XLR2, nullptr, P_NODES, 512, DOUT_, 4);
    gat_fused<2><<<P_NODES / 4, 256, 0, stream>>>(XLR2, offs, srcs, att2, bias2,
                                                  ln2g, ln2b, H1, out, nullptr);
}